// Round 10
// baseline (941.769 us; speedup 1.0000x reference)
//
#include <hip/hip_runtime.h>
#include <hip/hip_bf16.h>

#define DEV __device__ __forceinline__

static DEV float lrelu(float v) { return v >= 0.f ? v : 0.01f * v; }
static DEV float bflo(unsigned u) { return __uint_as_float(u << 16); }
static DEV float bfhi(unsigned u) { return __uint_as_float(u & 0xffff0000u); }

constexpr int BATCH = 256;

// ---- compact workspace layout (bytes) ----
// A: [0, 13107200)        p1 (bf16, ch-first) -> later h5 (bf16, CH-LAST [b][y][x][8])
// B: [13107200, 18350080) p2 (f32)  -> later h4 (f32)
// C: [18350080, 19398656) p3 (f32)
// D: [19398656, 20447232) dec (f32)
constexpr size_t BYTE_B = 13107200;
constexpr size_t BYTE_C = 18350080;
constexpr size_t BYTE_D = 19398656;

// ---------------------------------------------------------------- k1
// conv1 (6->8) + lrelu + maxpool 2x2, channel-last LDS + register tiling.
// __launch_bounds__(320, 1): loosest VGPR constraint (R9's (320) default strangled to 68 VGPR).
__global__ __launch_bounds__(320, 1) void k1_conv1_pool(
    const float* __restrict__ x, const float* __restrict__ w1,
    const float* __restrict__ b1, __hip_bfloat16* __restrict__ p1) {
  __shared__ float4 xs[3168];
  const int b = blockIdx.x, yt = blockIdx.y, tid = threadIdx.x;
  // ---- stage A: stage x into channel-last LDS (6 ch + 2 pad), halo zeroed
  for (int p = tid; p < 1560; p += 320) {
    const int lx = p % 130, ly = p / 130;
    const int gy = 10 * yt - 1 + ly, gx = lx - 1;
    float v[6];
    if ((unsigned)gy < 100u && (unsigned)gx < 128u) {
      #pragma unroll
      for (int c = 0; c < 6; ++c) v[c] = x[((size_t)(b * 6 + c) * 100 + gy) * 128 + gx];
    } else {
      #pragma unroll
      for (int c = 0; c < 6; ++c) v[c] = 0.f;
    }
    const int base = ly * 4224;
    const int sw = (((lx >> 2) & 7) << 4) ^ ((ly & 1) << 4);
    *(float4*)((char*)xs + base + ((lx * 32) ^ sw)) = make_float4(v[0], v[1], v[2], v[3]);
    *(float2*)((char*)xs + base + ((lx * 32 + 16) ^ sw)) = make_float2(v[4], v[5]);
  }
  __syncthreads();
  // ---- stage B: each thread computes 1 pooled output position for ALL 8 co
  const int oy = tid >> 6, ox = tid & 63;
  float ev[8][2][2];
  #pragma unroll
  for (int co = 0; co < 8; ++co) {
    const float bv = b1[co];
    #pragma unroll
    for (int dy = 0; dy < 2; ++dy)
      #pragma unroll
      for (int dx = 0; dx < 2; ++dx) ev[co][dy][dx] = bv;
  }
  #pragma unroll
  for (int t = 0; t < 4; ++t) {
    const int lr = 2 * oy + t;
    float inw[4][6];
    #pragma unroll
    for (int w = 0; w < 4; ++w) {
      const int lc = 2 * ox + w;
      const int base = lr * 4224;
      const int sw = (((lc >> 2) & 7) << 4) ^ ((lr & 1) << 4);
      const float4 lo = *(const float4*)((const char*)xs + base + ((lc * 32) ^ sw));
      const float2 hi = *(const float2*)((const char*)xs + base + ((lc * 32 + 16) ^ sw));
      inw[w][0] = lo.x; inw[w][1] = lo.y; inw[w][2] = lo.z;
      inw[w][3] = lo.w; inw[w][4] = hi.x; inw[w][5] = hi.y;
    }
    #pragma unroll
    for (int dy = 0; dy < 2; ++dy) {
      const int ky = t - dy;
      if (ky < 0 || ky > 2) continue;   // folds at compile time
      #pragma unroll
      for (int co = 0; co < 8; ++co)
        #pragma unroll
        for (int kx = 0; kx < 3; ++kx)
          #pragma unroll
          for (int ci = 0; ci < 6; ++ci) {
            const float wv = w1[(co * 6 + ci) * 9 + ky * 3 + kx];
            #pragma unroll
            for (int dx = 0; dx < 2; ++dx)
              ev[co][dy][dx] += inw[dx + kx][ci] * wv;
          }
    }
  }
  #pragma unroll
  for (int co = 0; co < 8; ++co) {
    const float m = fmaxf(fmaxf(lrelu(ev[co][0][0]), lrelu(ev[co][0][1])),
                          fmaxf(lrelu(ev[co][1][0]), lrelu(ev[co][1][1])));
    p1[((size_t)(b * 8 + co) * 50 + 5 * yt + oy) * 64 + ox] = __float2bfloat16(m);
  }
}

// ---------------------------------------------------------------- k2 (unchanged)
__global__ __launch_bounds__(256) void k2_conv2_pool(
    const __hip_bfloat16* __restrict__ p1, const float* __restrict__ w2,
    const float* __restrict__ b2, float* __restrict__ p2) {
  __shared__ float s1[8][7][66];
  __shared__ float wsh[1152];
  __shared__ float bsh[16];
  const int b = blockIdx.x, yt = blockIdx.y, tid = threadIdx.x;
  for (int i = tid; i < 1152; i += 256) wsh[i] = w2[i];
  if (tid < 16) bsh[tid] = b2[tid];
  for (int i = tid; i < 8 * 7 * 66; i += 256) {
    int col = i % 66, rem = i / 66, r = rem % 7, c = rem / 7;
    int gy = 5 * yt + r - 1, gx = col - 1;
    float v = 0.f;
    if (gy >= 0 && gy < 50 && (unsigned)gx < 64u)
      v = __bfloat162float(p1[((b * 8 + c) * 50 + gy) * 64 + gx]);
    s1[c][r][col] = v;
  }
  __syncthreads();
  for (int i = tid; i < 512; i += 256) {
    int ox = i & 31, co = i >> 5;
    float m = -1e30f;
    for (int dy = 0; dy < 5; ++dy)
      #pragma unroll
      for (int dx = 0; dx < 2; ++dx) {
        int cx = 2 * ox + dx;
        float acc = bsh[co];
        #pragma unroll
        for (int ci = 0; ci < 8; ++ci)
          #pragma unroll
          for (int ky = 0; ky < 3; ++ky)
            #pragma unroll
            for (int kx = 0; kx < 3; ++kx)
              acc += s1[ci][dy + ky][cx + kx] * wsh[(co * 8 + ci) * 9 + ky * 3 + kx];
        m = fmaxf(m, lrelu(acc));
      }
    p2[((b * 16 + co) * 10 + yt) * 32 + ox] = m;
  }
}

// ---------------------------------------------------------------- k3 (unchanged)
__global__ __launch_bounds__(256) void k3_conv3_pool(
    const float* __restrict__ p2, const float* __restrict__ w3,
    const float* __restrict__ b3, float* __restrict__ p3) {
  __shared__ float s2[16][12][34];
  __shared__ float wsh[4608];
  __shared__ float bsh[32];
  const int b = blockIdx.x, tid = threadIdx.x;
  for (int i = tid; i < 4608; i += 256) wsh[i] = w3[i];
  if (tid < 32) bsh[tid] = b3[tid];
  for (int i = tid; i < 16 * 12 * 34; i += 256) {
    int col = i % 34, rem = i / 34, r = rem % 12, c = rem / 12;
    int gy = r - 1, gx = col - 1;
    float v = 0.f;
    if ((unsigned)gy < 10u && (unsigned)gx < 32u)
      v = p2[((b * 16 + c) * 10 + gy) * 32 + gx];
    s2[c][r][col] = v;
  }
  __syncthreads();
  for (int i = tid; i < 1024; i += 256) {
    int ow = i & 15, rem = i >> 4, oh = rem & 1, co = rem >> 1;
    float m = -1e30f;
    for (int dy = 0; dy < 5; ++dy)
      #pragma unroll
      for (int dx = 0; dx < 2; ++dx) {
        int cy = 5 * oh + dy, cx = 2 * ow + dx;
        float acc = bsh[co];
        #pragma unroll
        for (int ci = 0; ci < 16; ++ci)
          #pragma unroll
          for (int ky = 0; ky < 3; ++ky)
            #pragma unroll
            for (int kx = 0; kx < 3; ++kx)
              acc += s2[ci][cy + ky][cx + kx] * wsh[(co * 16 + ci) * 9 + ky * 3 + kx];
        m = fmaxf(m, lrelu(acc));
      }
    p3[((b * 32 + co) * 2 + oh) * 16 + ow] = m;
  }
}

// ---------------------------------------------------------------- k4 (unchanged)
__global__ __launch_bounds__(64) void k4_latent(
    const float* __restrict__ p3, const float* __restrict__ eps,
    const float* __restrict__ wmu, const float* __restrict__ bmu,
    const float* __restrict__ wlv, const float* __restrict__ blv,
    const float* __restrict__ wlin, const float* __restrict__ blin,
    float* __restrict__ dec, float* __restrict__ out,
    size_t off_mu, size_t off_lv, size_t off_kld, size_t off_z) {
  const int b = blockIdx.x, t = threadIdx.x;
  __shared__ float skld[32];
  if (t < 32) {
    const int h = t >> 4, w = t & 15;
    float f[32];
    #pragma unroll
    for (int c = 0; c < 32; ++c) f[c] = p3[((b * 32 + c) * 2 + h) * 16 + w];
    const int n = b * 32 + t;
    float mu[4], lv[4], zz[4];
    #pragma unroll
    for (int j = 0; j < 4; ++j) {
      float m = bmu[j], l = blv[j];
      #pragma unroll
      for (int c = 0; c < 32; ++c) { m += f[c] * wmu[c * 4 + j]; l += f[c] * wlv[c * 4 + j]; }
      mu[j] = m; lv[j] = l;
      zz[j] = m + eps[n * 4 + j] * expf(0.5f * l);
    }
    float kc = 0.f;
    #pragma unroll
    for (int j = 0; j < 4; ++j) kc += 1.f + lv[j] - mu[j] * mu[j] - expf(lv[j]);
    skld[t] = -0.5f * kc;
    #pragma unroll
    for (int j = 0; j < 4; ++j) {
      out[off_mu + n * 4 + j] = mu[j];
      out[off_lv + n * 4 + j] = lv[j];
      out[off_z  + n * 4 + j] = zz[j];
    }
    for (int co = 0; co < 32; ++co) {
      float d = blin[co];
      #pragma unroll
      for (int j = 0; j < 4; ++j) d += zz[j] * wlin[j * 32 + co];
      dec[((b * 32 + co) * 2 + h) * 16 + w] = d;
    }
  }
  __syncthreads();
  if (t == 0) {
    float s = 0.f;
    for (int i = 0; i < 32; ++i) s += skld[i];
    out[off_kld + b] = s * (1.f / 32.f);
  }
}

// ---------------------------------------------------------------- k5 (unchanged)
__global__ __launch_bounds__(256) void k5_inv1_conv4(
    const float* __restrict__ dec, const float* __restrict__ wi1,
    const float* __restrict__ bi1, const float* __restrict__ w4,
    const float* __restrict__ b4, float* __restrict__ h4) {
  __shared__ float sdec[1024];
  __shared__ float su1[32][12][34];
  const int b = blockIdx.x, tid = threadIdx.x;
  for (int i = tid; i < 1024; i += 256) sdec[i] = dec[b * 1024 + i];
  for (int i = tid; i < 32 * 12 * 34; i += 256) ((float*)su1)[i] = 0.f;
  __syncthreads();
  for (int i = tid; i < 32 * 10 * 32; i += 256) {
    int X = i & 31, rem = i >> 5, Y = rem % 10, c = rem / 10;
    int hh = Y / 5, ky = Y % 5, wp = X >> 1, kx = X & 1;
    float acc = bi1[c];
    #pragma unroll
    for (int ci = 0; ci < 32; ++ci)
      acc += sdec[(ci * 2 + hh) * 16 + wp] * wi1[((ci * 32 + c) * 5 + ky) * 2 + kx];
    su1[c][Y + 1][X + 1] = lrelu(acc);
  }
  __syncthreads();
  for (int i = tid; i < 16 * 10 * 32; i += 256) {
    int X = i & 31, rem = i >> 5, Y = rem % 10, o = rem / 10;
    float acc = b4[o];
    for (int c = 0; c < 32; ++c)
      #pragma unroll
      for (int ky = 0; ky < 3; ++ky)
        #pragma unroll
        for (int kx = 0; kx < 3; ++kx)
          acc += su1[c][Y + ky][X + kx] * w4[((o * 32 + c) * 3 + ky) * 3 + kx];
    h4[((b * 16 + o) * 10 + Y) * 32 + X] = lrelu(acc);
  }
}

// ---------------------------------------------------------------- k6 (unchanged from R9; h5 store CHANNEL-LAST)
__global__ __launch_bounds__(256) void k6_inv2_conv5(
    const float* __restrict__ h4, const float* __restrict__ wi2,
    const float* __restrict__ bi2, const float* __restrict__ w5,
    const float* __restrict__ b5, __hip_bfloat16* __restrict__ h5) {
  __shared__ float su2[16][12][66];
  __shared__ float sh4[16][4][32];
  const int b = blockIdx.x, yt = blockIdx.y, tid = threadIdx.x;
  const int y0 = 10 * yt;
  const int r0 = (y0 == 0) ? 0 : (y0 - 1) / 5;
  for (int i = tid; i < 16 * 4 * 32; i += 256) {
    int xx = i & 31, rem = i >> 5, r = rem & 3, c = rem >> 2;
    int gr = r0 + r;
    sh4[c][r][xx] = (gr < 10) ? h4[((b * 16 + c) * 10 + gr) * 32 + xx] : 0.f;
  }
  __syncthreads();
  for (int i = tid; i < 16 * 12 * 66; i += 256) {
    int lx = i % 66, rem = i / 66, ly = rem % 12, c = rem / 12;
    int Y = y0 - 1 + ly, X = lx - 1;
    float v = 0.f;
    if ((unsigned)Y < 50u && (unsigned)X < 64u) {
      int hr = Y / 5 - r0, ky = Y % 5, hc = X >> 1, kx = X & 1;
      float acc = bi2[c];
      #pragma unroll
      for (int ci = 0; ci < 16; ++ci)
        acc += sh4[ci][hr][hc] * wi2[((ci * 16 + c) * 5 + ky) * 2 + kx];
      v = lrelu(acc);
    }
    su2[c][ly][lx] = v;
  }
  __syncthreads();
  for (int i = tid; i < 8 * 10 * 64; i += 256) {
    int X = i & 63, rem = i >> 6, Y = rem % 10, o = rem / 10;
    float acc = b5[o];
    for (int c = 0; c < 16; ++c)
      #pragma unroll
      for (int ky = 0; ky < 3; ++ky)
        #pragma unroll
        for (int kx = 0; kx < 3; ++kx)
          acc += su2[c][Y + ky][X + kx] * w5[((o * 16 + c) * 3 + ky) * 3 + kx];
    h5[(((size_t)b * 50 + y0 + Y) * 64 + X) * 8 + o] = __float2bfloat16(lrelu(acc));
  }
}

// ---------------------------------------------------------------- k7
// invconv3(8->8,2x2)+lrelu into channel-last swizzled LDS, then conv6(8->6).
// __launch_bounds__(320, 1): fix R9's VGPR strangulation (68 VGPR -> expect >=110).
__global__ __launch_bounds__(320, 1) void k7_inv3_conv6(
    const __hip_bfloat16* __restrict__ h5, const float* __restrict__ wi3,
    const float* __restrict__ bi3, const float* __restrict__ w6,
    const float* __restrict__ b6, float* __restrict__ out) {
  __shared__ float4 su[3168];
  const int b = blockIdx.x, yt = blockIdx.y, tid = threadIdx.x;
  const int y0 = 10 * yt;
  // ---- stage 1: u3 = lrelu(invconv3(h5)), parity-class threads (uniform ky,kx per thread)
  {
    const int lyp = (tid >> 1) & 1, lxp = tid & 1;
    const int ky = (lyp + 1) & 1, kx = (lxp + 1) & 1;
    float wr[8][8];
    #pragma unroll
    for (int ci = 0; ci < 8; ++ci)
      #pragma unroll
      for (int c = 0; c < 8; ++c)
        wr[ci][c] = wi3[((ci * 8 + c) * 2 + ky) * 2 + kx];
    float bs[8];
    #pragma unroll
    for (int c = 0; c < 8; ++c) bs[c] = bi3[c];
    for (int p = tid >> 2; p < 390; p += 80) {
      const int ly = lyp + 2 * (p / 65);
      const int lx = lxp + 2 * (p % 65);
      const int yy = y0 - 1 + ly, xx2 = lx - 1;
      float u[8];
      if ((unsigned)yy < 100u && (unsigned)xx2 < 128u) {
        const uint4 hv = *(const uint4*)&h5[(((size_t)b * 50 + (yy >> 1)) * 64 + (xx2 >> 1)) * 8];
        const float v0 = bflo(hv.x), v1 = bfhi(hv.x), v2 = bflo(hv.y), v3 = bfhi(hv.y);
        const float v4 = bflo(hv.z), v5 = bfhi(hv.z), v6 = bflo(hv.w), v7 = bfhi(hv.w);
        #pragma unroll
        for (int c = 0; c < 8; ++c) {
          float a = bs[c];
          a += v0 * wr[0][c]; a += v1 * wr[1][c]; a += v2 * wr[2][c]; a += v3 * wr[3][c];
          a += v4 * wr[4][c]; a += v5 * wr[5][c]; a += v6 * wr[6][c]; a += v7 * wr[7][c];
          u[c] = lrelu(a);
        }
      } else {
        #pragma unroll
        for (int c = 0; c < 8; ++c) u[c] = 0.f;
      }
      const int base = ly * 4224;
      const int sw = (((lx >> 2) & 7) << 4) ^ ((ly & 1) << 4);
      *(float4*)((char*)su + base + ((lx * 32) ^ sw)) = make_float4(u[0], u[1], u[2], u[3]);
      *(float4*)((char*)su + base + ((lx * 32 + 16) ^ sw)) = make_float4(u[4], u[5], u[6], u[7]);
    }
  }
  __syncthreads();
  // ---- stage 2: conv6, thread = (Y, 4-wide x-tile), all 6 co
  {
    const int Y = tid >> 5, xt = tid & 31, X0 = xt * 4;
    float acc[6][4];
    #pragma unroll
    for (int o = 0; o < 6; ++o) {
      const float bv = b6[o];
      #pragma unroll
      for (int xx = 0; xx < 4; ++xx) acc[o][xx] = bv;
    }
    #pragma unroll
    for (int ky = 0; ky < 3; ++ky) {
      const int lr = Y + ky;
      const int base = lr * 4224;
      const int rsw = (lr & 1) << 4;
      float inw[6][8];
      #pragma unroll
      for (int w = 0; w < 6; ++w) {
        const int lc = X0 + w;
        const int sw = ((((lc >> 2) & 7) << 4)) ^ rsw;
        const float4 lo = *(const float4*)((const char*)su + base + ((lc * 32) ^ sw));
        const float4 hi = *(const float4*)((const char*)su + base + ((lc * 32 + 16) ^ sw));
        inw[w][0] = lo.x; inw[w][1] = lo.y; inw[w][2] = lo.z; inw[w][3] = lo.w;
        inw[w][4] = hi.x; inw[w][5] = hi.y; inw[w][6] = hi.z; inw[w][7] = hi.w;
      }
      #pragma unroll
      for (int o = 0; o < 6; ++o)
        #pragma unroll
        for (int kx = 0; kx < 3; ++kx)
          #pragma unroll
          for (int ci = 0; ci < 8; ++ci) {
            const float wv = w6[((o * 8 + ci) * 3 + ky) * 3 + kx];
            #pragma unroll
            for (int xx = 0; xx < 4; ++xx)
              acc[o][xx] += inw[kx + xx][ci] * wv;
          }
    }
    #pragma unroll
    for (int o = 0; o < 6; ++o) {
      float* op = &out[((size_t)(b * 6 + o) * 100 + y0 + Y) * 128 + X0];
      *(float4*)op = make_float4(acc[o][0], acc[o][1], acc[o][2], acc[o][3]);
    }
  }
}

// ---------------------------------------------------------------- launch
extern "C" void kernel_launch(void* const* d_in, const int* in_sizes, int n_in,
                              void* d_out, int out_size, void* d_ws, size_t ws_size,
                              hipStream_t stream) {
  const float* x    = (const float*)d_in[0];
  const float* eps  = (const float*)d_in[1];
  const float* w1   = (const float*)d_in[2];
  const float* b1   = (const float*)d_in[3];
  const float* w2   = (const float*)d_in[4];
  const float* b2   = (const float*)d_in[5];
  const float* w3   = (const float*)d_in[6];
  const float* b3   = (const float*)d_in[7];
  const float* wmu  = (const float*)d_in[8];
  const float* bmu  = (const float*)d_in[9];
  const float* wlv  = (const float*)d_in[10];
  const float* blv  = (const float*)d_in[11];
  const float* wlin = (const float*)d_in[12];
  const float* blin = (const float*)d_in[13];
  const float* wi1  = (const float*)d_in[14];
  const float* bi1  = (const float*)d_in[15];
  const float* w4   = (const float*)d_in[16];
  const float* b4   = (const float*)d_in[17];
  const float* wi2  = (const float*)d_in[18];
  const float* bi2  = (const float*)d_in[19];
  const float* w5   = (const float*)d_in[20];
  const float* b5   = (const float*)d_in[21];
  const float* wi3  = (const float*)d_in[22];
  const float* bi3  = (const float*)d_in[23];
  const float* w6   = (const float*)d_in[24];
  const float* b6   = (const float*)d_in[25];

  char* wsb = (char*)d_ws;
  __hip_bfloat16* p1 = (__hip_bfloat16*)wsb;          // region A
  __hip_bfloat16* h5 = (__hip_bfloat16*)wsb;          // region A (alias, p1 dead)
  float* p2  = (float*)(wsb + BYTE_B);                // region B
  float* h4  = (float*)(wsb + BYTE_B);                // region B (alias, p2 dead)
  float* p3  = (float*)(wsb + BYTE_C);
  float* dec = (float*)(wsb + BYTE_D);
  float* out = (float*)d_out;                         // OUTPUT IS FLOAT32

  // element offsets into f32 out: [out | mu | logvar | kld | z]
  const size_t off_z   = (size_t)out_size - 32768;
  const size_t off_kld = off_z - 256;
  const size_t off_lv  = off_kld - 32768;
  const size_t off_mu  = off_lv - 32768;

  k1_conv1_pool<<<dim3(BATCH, 10), 320, 0, stream>>>(x, w1, b1, p1);
  k2_conv2_pool<<<dim3(BATCH, 10), 256, 0, stream>>>(p1, w2, b2, p2);
  k3_conv3_pool<<<dim3(BATCH), 256, 0, stream>>>(p2, w3, b3, p3);
  k4_latent<<<dim3(BATCH), 64, 0, stream>>>(p3, eps, wmu, bmu, wlv, blv, wlin, blin,
                                            dec, out, off_mu, off_lv, off_kld, off_z);
  k5_inv1_conv4<<<dim3(BATCH), 256, 0, stream>>>(dec, wi1, bi1, w4, b4, h4);
  k6_inv2_conv5<<<dim3(BATCH, 5), 256, 0, stream>>>(h4, wi2, bi2, w5, b5, h5);
  k7_inv3_conv6<<<dim3(BATCH, 10), 320, 0, stream>>>(h5, wi3, bi3, w6, b6, out);
}

// Round 11
// 646.498 us; speedup vs baseline: 1.4567x; 1.4567x over previous
//
#include <hip/hip_runtime.h>
#include <hip/hip_bf16.h>

#define DEV __device__ __forceinline__

static DEV float lrelu(float v) { return v >= 0.f ? v : 0.01f * v; }
static DEV float bflo(unsigned u) { return __uint_as_float(u << 16); }
static DEV float bfhi(unsigned u) { return __uint_as_float(u & 0xffff0000u); }

constexpr int BATCH = 256;

// ---- compact workspace layout (bytes) ----
// A: [0, 13107200)        p1 (bf16, ch-first) -> later h5 (bf16, CH-LAST [b][y][x][8])
// B: [13107200, 18350080) p2 (f32)  -> later h4 (f32)
// C: [18350080, 19398656) p3 (f32)
// D: [19398656, 20447232) dec (f32)
constexpr size_t BYTE_B = 13107200;
constexpr size_t BYTE_C = 18350080;
constexpr size_t BYTE_D = 19398656;

// ---------------------------------------------------------------- k1 (R8-proven version)
__global__ __launch_bounds__(256) void k1_conv1_pool(
    const float* __restrict__ x, const float* __restrict__ w1,
    const float* __restrict__ b1, __hip_bfloat16* __restrict__ p1) {
  __shared__ float xs[6][12][130];
  __shared__ float wsh[432];
  __shared__ float bsh[8];
  const int b = blockIdx.x, yt = blockIdx.y, tid = threadIdx.x;
  for (int i = tid; i < 432; i += 256) wsh[i] = w1[i];
  if (tid < 8) bsh[tid] = b1[tid];
  for (int i = tid; i < 6 * 12 * 130; i += 256) {
    int col = i % 130, rem = i / 130, r = rem % 12, c = rem / 12;
    int gy = 10 * yt + r - 1, gx = col - 1;
    float v = 0.f;
    if (gy >= 0 && gy < 100 && (unsigned)gx < 128u)
      v = x[((b * 6 + c) * 100 + gy) * 128 + gx];
    xs[c][r][col] = v;
  }
  __syncthreads();
  for (int i = tid; i < 2560; i += 256) {
    int ox = i & 63, rem = i >> 6, oy = rem % 5, co = rem / 5;
    float m = -1e30f;
    #pragma unroll
    for (int dy = 0; dy < 2; ++dy)
      #pragma unroll
      for (int dx = 0; dx < 2; ++dx) {
        int cy = 2 * oy + dy, cx = 2 * ox + dx;
        float acc = bsh[co];
        #pragma unroll
        for (int ci = 0; ci < 6; ++ci)
          #pragma unroll
          for (int ky = 0; ky < 3; ++ky)
            #pragma unroll
            for (int kx = 0; kx < 3; ++kx)
              acc += xs[ci][cy + ky][cx + kx] * wsh[(co * 6 + ci) * 9 + ky * 3 + kx];
        m = fmaxf(m, lrelu(acc));
      }
    p1[((b * 8 + co) * 50 + 5 * yt + oy) * 64 + ox] = __float2bfloat16(m);
  }
}

// ---------------------------------------------------------------- k2 (unchanged)
__global__ __launch_bounds__(256) void k2_conv2_pool(
    const __hip_bfloat16* __restrict__ p1, const float* __restrict__ w2,
    const float* __restrict__ b2, float* __restrict__ p2) {
  __shared__ float s1[8][7][66];
  __shared__ float wsh[1152];
  __shared__ float bsh[16];
  const int b = blockIdx.x, yt = blockIdx.y, tid = threadIdx.x;
  for (int i = tid; i < 1152; i += 256) wsh[i] = w2[i];
  if (tid < 16) bsh[tid] = b2[tid];
  for (int i = tid; i < 8 * 7 * 66; i += 256) {
    int col = i % 66, rem = i / 66, r = rem % 7, c = rem / 7;
    int gy = 5 * yt + r - 1, gx = col - 1;
    float v = 0.f;
    if (gy >= 0 && gy < 50 && (unsigned)gx < 64u)
      v = __bfloat162float(p1[((b * 8 + c) * 50 + gy) * 64 + gx]);
    s1[c][r][col] = v;
  }
  __syncthreads();
  for (int i = tid; i < 512; i += 256) {
    int ox = i & 31, co = i >> 5;
    float m = -1e30f;
    for (int dy = 0; dy < 5; ++dy)
      #pragma unroll
      for (int dx = 0; dx < 2; ++dx) {
        int cx = 2 * ox + dx;
        float acc = bsh[co];
        #pragma unroll
        for (int ci = 0; ci < 8; ++ci)
          #pragma unroll
          for (int ky = 0; ky < 3; ++ky)
            #pragma unroll
            for (int kx = 0; kx < 3; ++kx)
              acc += s1[ci][dy + ky][cx + kx] * wsh[(co * 8 + ci) * 9 + ky * 3 + kx];
        m = fmaxf(m, lrelu(acc));
      }
    p2[((b * 16 + co) * 10 + yt) * 32 + ox] = m;
  }
}

// ---------------------------------------------------------------- k3 (unchanged)
__global__ __launch_bounds__(256) void k3_conv3_pool(
    const float* __restrict__ p2, const float* __restrict__ w3,
    const float* __restrict__ b3, float* __restrict__ p3) {
  __shared__ float s2[16][12][34];
  __shared__ float wsh[4608];
  __shared__ float bsh[32];
  const int b = blockIdx.x, tid = threadIdx.x;
  for (int i = tid; i < 4608; i += 256) wsh[i] = w3[i];
  if (tid < 32) bsh[tid] = b3[tid];
  for (int i = tid; i < 16 * 12 * 34; i += 256) {
    int col = i % 34, rem = i / 34, r = rem % 12, c = rem / 12;
    int gy = r - 1, gx = col - 1;
    float v = 0.f;
    if ((unsigned)gy < 10u && (unsigned)gx < 32u)
      v = p2[((b * 16 + c) * 10 + gy) * 32 + gx];
    s2[c][r][col] = v;
  }
  __syncthreads();
  for (int i = tid; i < 1024; i += 256) {
    int ow = i & 15, rem = i >> 4, oh = rem & 1, co = rem >> 1;
    float m = -1e30f;
    for (int dy = 0; dy < 5; ++dy)
      #pragma unroll
      for (int dx = 0; dx < 2; ++dx) {
        int cy = 5 * oh + dy, cx = 2 * ow + dx;
        float acc = bsh[co];
        #pragma unroll
        for (int ci = 0; ci < 16; ++ci)
          #pragma unroll
          for (int ky = 0; ky < 3; ++ky)
            #pragma unroll
            for (int kx = 0; kx < 3; ++kx)
              acc += s2[ci][cy + ky][cx + kx] * wsh[(co * 16 + ci) * 9 + ky * 3 + kx];
        m = fmaxf(m, lrelu(acc));
      }
    p3[((b * 32 + co) * 2 + oh) * 16 + ow] = m;
  }
}

// ---------------------------------------------------------------- k4 (unchanged)
__global__ __launch_bounds__(64) void k4_latent(
    const float* __restrict__ p3, const float* __restrict__ eps,
    const float* __restrict__ wmu, const float* __restrict__ bmu,
    const float* __restrict__ wlv, const float* __restrict__ blv,
    const float* __restrict__ wlin, const float* __restrict__ blin,
    float* __restrict__ dec, float* __restrict__ out,
    size_t off_mu, size_t off_lv, size_t off_kld, size_t off_z) {
  const int b = blockIdx.x, t = threadIdx.x;
  __shared__ float skld[32];
  if (t < 32) {
    const int h = t >> 4, w = t & 15;
    float f[32];
    #pragma unroll
    for (int c = 0; c < 32; ++c) f[c] = p3[((b * 32 + c) * 2 + h) * 16 + w];
    const int n = b * 32 + t;
    float mu[4], lv[4], zz[4];
    #pragma unroll
    for (int j = 0; j < 4; ++j) {
      float m = bmu[j], l = blv[j];
      #pragma unroll
      for (int c = 0; c < 32; ++c) { m += f[c] * wmu[c * 4 + j]; l += f[c] * wlv[c * 4 + j]; }
      mu[j] = m; lv[j] = l;
      zz[j] = m + eps[n * 4 + j] * expf(0.5f * l);
    }
    float kc = 0.f;
    #pragma unroll
    for (int j = 0; j < 4; ++j) kc += 1.f + lv[j] - mu[j] * mu[j] - expf(lv[j]);
    skld[t] = -0.5f * kc;
    #pragma unroll
    for (int j = 0; j < 4; ++j) {
      out[off_mu + n * 4 + j] = mu[j];
      out[off_lv + n * 4 + j] = lv[j];
      out[off_z  + n * 4 + j] = zz[j];
    }
    for (int co = 0; co < 32; ++co) {
      float d = blin[co];
      #pragma unroll
      for (int j = 0; j < 4; ++j) d += zz[j] * wlin[j * 32 + co];
      dec[((b * 32 + co) * 2 + h) * 16 + w] = d;
    }
  }
  __syncthreads();
  if (t == 0) {
    float s = 0.f;
    for (int i = 0; i < 32; ++i) s += skld[i];
    out[off_kld + b] = s * (1.f / 32.f);
  }
}

// ---------------------------------------------------------------- k5 (unchanged)
__global__ __launch_bounds__(256) void k5_inv1_conv4(
    const float* __restrict__ dec, const float* __restrict__ wi1,
    const float* __restrict__ bi1, const float* __restrict__ w4,
    const float* __restrict__ b4, float* __restrict__ h4) {
  __shared__ float sdec[1024];
  __shared__ float su1[32][12][34];
  const int b = blockIdx.x, tid = threadIdx.x;
  for (int i = tid; i < 1024; i += 256) sdec[i] = dec[b * 1024 + i];
  for (int i = tid; i < 32 * 12 * 34; i += 256) ((float*)su1)[i] = 0.f;
  __syncthreads();
  for (int i = tid; i < 32 * 10 * 32; i += 256) {
    int X = i & 31, rem = i >> 5, Y = rem % 10, c = rem / 10;
    int hh = Y / 5, ky = Y % 5, wp = X >> 1, kx = X & 1;
    float acc = bi1[c];
    #pragma unroll
    for (int ci = 0; ci < 32; ++ci)
      acc += sdec[(ci * 2 + hh) * 16 + wp] * wi1[((ci * 32 + c) * 5 + ky) * 2 + kx];
    su1[c][Y + 1][X + 1] = lrelu(acc);
  }
  __syncthreads();
  for (int i = tid; i < 16 * 10 * 32; i += 256) {
    int X = i & 31, rem = i >> 5, Y = rem % 10, o = rem / 10;
    float acc = b4[o];
    for (int c = 0; c < 32; ++c)
      #pragma unroll
      for (int ky = 0; ky < 3; ++ky)
        #pragma unroll
        for (int kx = 0; kx < 3; ++kx)
          acc += su1[c][Y + ky][X + kx] * w4[((o * 32 + c) * 3 + ky) * 3 + kx];
    h4[((b * 16 + o) * 10 + Y) * 32 + X] = lrelu(acc);
  }
}

// ---------------------------------------------------------------- k6 (unchanged; h5 store CHANNEL-LAST)
__global__ __launch_bounds__(256) void k6_inv2_conv5(
    const float* __restrict__ h4, const float* __restrict__ wi2,
    const float* __restrict__ bi2, const float* __restrict__ w5,
    const float* __restrict__ b5, __hip_bfloat16* __restrict__ h5) {
  __shared__ float su2[16][12][66];
  __shared__ float sh4[16][4][32];
  const int b = blockIdx.x, yt = blockIdx.y, tid = threadIdx.x;
  const int y0 = 10 * yt;
  const int r0 = (y0 == 0) ? 0 : (y0 - 1) / 5;
  for (int i = tid; i < 16 * 4 * 32; i += 256) {
    int xx = i & 31, rem = i >> 5, r = rem & 3, c = rem >> 2;
    int gr = r0 + r;
    sh4[c][r][xx] = (gr < 10) ? h4[((b * 16 + c) * 10 + gr) * 32 + xx] : 0.f;
  }
  __syncthreads();
  for (int i = tid; i < 16 * 12 * 66; i += 256) {
    int lx = i % 66, rem = i / 66, ly = rem % 12, c = rem / 12;
    int Y = y0 - 1 + ly, X = lx - 1;
    float v = 0.f;
    if ((unsigned)Y < 50u && (unsigned)X < 64u) {
      int hr = Y / 5 - r0, ky = Y % 5, hc = X >> 1, kx = X & 1;
      float acc = bi2[c];
      #pragma unroll
      for (int ci = 0; ci < 16; ++ci)
        acc += sh4[ci][hr][hc] * wi2[((ci * 16 + c) * 5 + ky) * 2 + kx];
      v = lrelu(acc);
    }
    su2[c][ly][lx] = v;
  }
  __syncthreads();
  for (int i = tid; i < 8 * 10 * 64; i += 256) {
    int X = i & 63, rem = i >> 6, Y = rem % 10, o = rem / 10;
    float acc = b5[o];
    for (int c = 0; c < 16; ++c)
      #pragma unroll
      for (int ky = 0; ky < 3; ++ky)
        #pragma unroll
        for (int kx = 0; kx < 3; ++kx)
          acc += su2[c][Y + ky][X + kx] * w5[((o * 16 + c) * 3 + ky) * 3 + kx];
    h5[(((size_t)b * 50 + y0 + Y) * 64 + X) * 8 + o] = __float2bfloat16(lrelu(acc));
  }
}

// ---------------------------------------------------------------- k7 v3
// Stage 1: invconv3+lrelu -> ch-last swizzled LDS (identical logic to passing R9/R10).
// Stage 2: conv6 with acc[5][6] register tile; weights LDS-staged [k][o][ci],
//          hoisted 48/iteration via uniform broadcast reads. 256 thr, (256,1).
__global__ __launch_bounds__(256, 1) void k7_inv3_conv6(
    const __hip_bfloat16* __restrict__ h5, const float* __restrict__ wi3,
    const float* __restrict__ bi3, const float* __restrict__ w6,
    const float* __restrict__ b6, float* __restrict__ out) {
  __shared__ float4 su[3168];   // 50688 B
  __shared__ float wsh[432];    // w6 as [k=ky*3+kx][o][ci]
  __shared__ float bsh[6];
  const int b = blockIdx.x, yt = blockIdx.y, tid = threadIdx.x;
  const int y0 = 10 * yt;
  // stage weights/bias
  for (int i = tid; i < 432; i += 256) {
    const int ci = i & 7, rem = i >> 3, o = rem % 6, k = rem / 6;
    wsh[i] = w6[((o * 8 + ci) * 3 + (k / 3)) * 3 + (k % 3)];
  }
  if (tid < 6) bsh[tid] = b6[tid];
  // ---- stage 1: u3 = lrelu(invconv3(h5)), parity-class threads
  {
    const int lyp = (tid >> 1) & 1, lxp = tid & 1;
    const int ky = (lyp + 1) & 1, kx = (lxp + 1) & 1;
    float wr[8][8];
    #pragma unroll
    for (int ci = 0; ci < 8; ++ci)
      #pragma unroll
      for (int c = 0; c < 8; ++c)
        wr[ci][c] = wi3[((ci * 8 + c) * 2 + ky) * 2 + kx];
    float bs[8];
    #pragma unroll
    for (int c = 0; c < 8; ++c) bs[c] = bi3[c];
    for (int p = tid >> 2; p < 390; p += 64) {
      const int ly = lyp + 2 * (p / 65);
      const int lx = lxp + 2 * (p % 65);
      const int yy = y0 - 1 + ly, xx2 = lx - 1;
      float u[8];
      if ((unsigned)yy < 100u && (unsigned)xx2 < 128u) {
        const uint4 hv = *(const uint4*)&h5[(((size_t)b * 50 + (yy >> 1)) * 64 + (xx2 >> 1)) * 8];
        const float v0 = bflo(hv.x), v1 = bfhi(hv.x), v2 = bflo(hv.y), v3 = bfhi(hv.y);
        const float v4 = bflo(hv.z), v5 = bfhi(hv.z), v6 = bflo(hv.w), v7 = bfhi(hv.w);
        #pragma unroll
        for (int c = 0; c < 8; ++c) {
          float a = bs[c];
          a += v0 * wr[0][c]; a += v1 * wr[1][c]; a += v2 * wr[2][c]; a += v3 * wr[3][c];
          a += v4 * wr[4][c]; a += v5 * wr[5][c]; a += v6 * wr[6][c]; a += v7 * wr[7][c];
          u[c] = lrelu(a);
        }
      } else {
        #pragma unroll
        for (int c = 0; c < 8; ++c) u[c] = 0.f;
      }
      const int base = ly * 4224;
      const int sw = (((lx >> 2) & 7) << 4) ^ ((ly & 1) << 4);
      *(float4*)((char*)su + base + ((lx * 32) ^ sw)) = make_float4(u[0], u[1], u[2], u[3]);
      *(float4*)((char*)su + base + ((lx * 32 + 16) ^ sw)) = make_float4(u[4], u[5], u[6], u[7]);
    }
  }
  __syncthreads();
  // ---- stage 2: conv6; thread = (x, y-parity), 5 rows x 6 channels in registers
  {
    const int x = tid & 127, yb = tid >> 7;   // x 0..127, yb 0..1
    float acc[5][6];
    #pragma unroll
    for (int r = 0; r < 5; ++r)
      #pragma unroll
      for (int o = 0; o < 6; ++o) acc[r][o] = bsh[o];
    #pragma unroll
    for (int k = 0; k < 9; ++k) {            // k = ky*3+kx
      const int ky = k / 3, kx = k % 3;
      float wr[6][8];
      #pragma unroll
      for (int o = 0; o < 6; ++o) {          // uniform-address broadcast reads
        const float4 wlo = *(const float4*)&wsh[(k * 6 + o) * 8];
        const float4 whi = *(const float4*)&wsh[(k * 6 + o) * 8 + 4];
        wr[o][0] = wlo.x; wr[o][1] = wlo.y; wr[o][2] = wlo.z; wr[o][3] = wlo.w;
        wr[o][4] = whi.x; wr[o][5] = whi.y; wr[o][6] = whi.z; wr[o][7] = whi.w;
      }
      const int lc = x + kx;
      const int csw = ((lc >> 2) & 7) << 4;
      #pragma unroll
      for (int r = 0; r < 5; ++r) {
        const int lr = yb + 2 * r + ky;
        const int base = lr * 4224;
        const int sw = csw ^ ((lr & 1) << 4);
        const float4 lo = *(const float4*)((const char*)su + base + ((lc * 32) ^ sw));
        const float4 hi = *(const float4*)((const char*)su + base + ((lc * 32 + 16) ^ sw));
        const float v[8] = {lo.x, lo.y, lo.z, lo.w, hi.x, hi.y, hi.z, hi.w};
        #pragma unroll
        for (int o = 0; o < 6; ++o)
          #pragma unroll
          for (int ci = 0; ci < 8; ++ci)
            acc[r][o] += v[ci] * wr[o][ci];
      }
    }
    #pragma unroll
    for (int r = 0; r < 5; ++r) {
      const int Y = y0 + yb + 2 * r;
      #pragma unroll
      for (int o = 0; o < 6; ++o)
        out[((size_t)(b * 6 + o) * 100 + Y) * 128 + x] = acc[r][o];
    }
  }
}

// ---------------------------------------------------------------- launch
extern "C" void kernel_launch(void* const* d_in, const int* in_sizes, int n_in,
                              void* d_out, int out_size, void* d_ws, size_t ws_size,
                              hipStream_t stream) {
  const float* x    = (const float*)d_in[0];
  const float* eps  = (const float*)d_in[1];
  const float* w1   = (const float*)d_in[2];
  const float* b1   = (const float*)d_in[3];
  const float* w2   = (const float*)d_in[4];
  const float* b2   = (const float*)d_in[5];
  const float* w3   = (const float*)d_in[6];
  const float* b3   = (const float*)d_in[7];
  const float* wmu  = (const float*)d_in[8];
  const float* bmu  = (const float*)d_in[9];
  const float* wlv  = (const float*)d_in[10];
  const float* blv  = (const float*)d_in[11];
  const float* wlin = (const float*)d_in[12];
  const float* blin = (const float*)d_in[13];
  const float* wi1  = (const float*)d_in[14];
  const float* bi1  = (const float*)d_in[15];
  const float* w4   = (const float*)d_in[16];
  const float* b4   = (const float*)d_in[17];
  const float* wi2  = (const float*)d_in[18];
  const float* bi2  = (const float*)d_in[19];
  const float* w5   = (const float*)d_in[20];
  const float* b5   = (const float*)d_in[21];
  const float* wi3  = (const float*)d_in[22];
  const float* bi3  = (const float*)d_in[23];
  const float* w6   = (const float*)d_in[24];
  const float* b6   = (const float*)d_in[25];

  char* wsb = (char*)d_ws;
  __hip_bfloat16* p1 = (__hip_bfloat16*)wsb;          // region A
  __hip_bfloat16* h5 = (__hip_bfloat16*)wsb;          // region A (alias, p1 dead)
  float* p2  = (float*)(wsb + BYTE_B);                // region B
  float* h4  = (float*)(wsb + BYTE_B);                // region B (alias, p2 dead)
  float* p3  = (float*)(wsb + BYTE_C);
  float* dec = (float*)(wsb + BYTE_D);
  float* out = (float*)d_out;                         // OUTPUT IS FLOAT32

  // element offsets into f32 out: [out | mu | logvar | kld | z]
  const size_t off_z   = (size_t)out_size - 32768;
  const size_t off_kld = off_z - 256;
  const size_t off_lv  = off_kld - 32768;
  const size_t off_mu  = off_lv - 32768;

  k1_conv1_pool<<<dim3(BATCH, 10), 256, 0, stream>>>(x, w1, b1, p1);
  k2_conv2_pool<<<dim3(BATCH, 10), 256, 0, stream>>>(p1, w2, b2, p2);
  k3_conv3_pool<<<dim3(BATCH), 256, 0, stream>>>(p2, w3, b3, p3);
  k4_latent<<<dim3(BATCH), 64, 0, stream>>>(p3, eps, wmu, bmu, wlv, blv, wlin, blin,
                                            dec, out, off_mu, off_lv, off_kld, off_z);
  k5_inv1_conv4<<<dim3(BATCH), 256, 0, stream>>>(dec, wi1, bi1, w4, b4, h4);
  k6_inv2_conv5<<<dim3(BATCH, 5), 256, 0, stream>>>(h4, wi2, bi2, w5, b5, h5);
  k7_inv3_conv6<<<dim3(BATCH, 10), 256, 0, stream>>>(h5, wi3, bi3, w6, b6, out);
}